// Round 1
// 266.688 us; speedup vs baseline: 1.1440x; 1.1440x over previous
//
#include <hip/hip_runtime.h>
#include <cstdint>

// ---------------- workspace layout (float offsets) ----------------
#define WS_U      0                          // 3*8*512 = 12288
#define WS_C0     12288                      // 24 (unused now)
#define WS_ENTBM  12312                      // 1
#define WS_ENTP   12320                      // 8*512 = 4096
#define WS_P      16416                      // 1536*4096 = 6291456
#define WS_OUT2   WS_P                       // alias (P dead after vout GEMM)
#define WS_GPRE   (WS_P + 786432)            // 3 partials * 262144
#define WS_HFUSED (WS_P + 1572864)           // 262144
#define WS_ENHPRE (WS_P + 1835008)           // 2 partials * 262144
#define WS_VOUT   (WS_P + 6291456)           // 786432
#define WS_HCAT   (WS_VOUT + 786432)         // 786432
#define WS_H      (WS_HCAT + 786432)         // 1536
#define WS_Z      (WS_H + 1536)              // 1536

__device__ __forceinline__ float blk_sum4(float v, float* red, int lane, int wave) {
#pragma unroll
  for (int off = 32; off; off >>= 1) v += __shfl_xor(v, off);
  __syncthreads();
  if (lane == 0) red[wave] = v;
  __syncthreads();
  return red[0] + red[1] + red[2] + red[3];
}

// ---------------- prep: grid (4, 8); m<3 -> u vectors, m==3 -> ent partials ----------------
__global__ __launch_bounds__(256) void prep_kernel(
    const float* __restrict__ qrgb, const float* __restrict__ qnir, const float* __restrict__ qtir,
    const float* __restrict__ inw, const float* __restrict__ inb,
    const float* __restrict__ entw, const float* __restrict__ entb,
    float* __restrict__ ws)
{
  const int m = blockIdx.x, h = blockIdx.y;
  const int tid = threadIdx.x, lane = tid & 63, wave = tid >> 6;
  __shared__ float qvl[64];
  __shared__ float red[4];

  if (m == 3) {
    // ent_w column partial sums, slice h
    const float* base = entw + (size_t)h * 64 * 512;
    float acc0 = 0.f, acc1 = 0.f;
#pragma unroll 8
    for (int r = 0; r < 64; r++) {
      acc0 += base[(size_t)r * 512 + tid];
      acc1 += base[(size_t)r * 512 + tid + 256];
    }
    ws[WS_ENTP + h * 512 + tid] = acc0;
    ws[WS_ENTP + h * 512 + tid + 256] = acc1;
    return;
  }

  const float* qry = (m == 0) ? qrgb : (m == 1) ? qnir : qtir;
  float4 q0 = *(const float4*)(qry + 4 * lane);
  float4 q1 = *(const float4*)(qry + 256 + 4 * lane);
  // qv[d] = q . Wq[h*64+d] + bq
#pragma unroll 4
  for (int dd = 0; dd < 16; dd++) {
    const int d = wave * 16 + dd;
    const float* wr = inw + (size_t)(h * 64 + d) * 512;
    float4 w0 = *(const float4*)(wr + 4 * lane);
    float4 w1 = *(const float4*)(wr + 256 + 4 * lane);
    float p = w0.x * q0.x + w0.y * q0.y + w0.z * q0.z + w0.w * q0.w
            + w1.x * q1.x + w1.y * q1.y + w1.z * q1.z + w1.w * q1.w;
#pragma unroll
    for (int off = 32; off; off >>= 1) p += __shfl_xor(p, off);
    if (lane == 0) qvl[d] = p + inb[h * 64 + d];
  }
  __syncthreads();
  // u[m][h][c] = 0.125 * sum_d qvl[d] * Wk[h*64+d][c]   (c0 dropped: softmax shift-invariant)
  float acc0 = 0.f, acc1 = 0.f;
  const float* wk = inw + (size_t)(512 + h * 64) * 512;
#pragma unroll 8
  for (int d = 0; d < 64; d++) {
    float qq = qvl[d];
    acc0 = fmaf(qq, wk[(size_t)d * 512 + tid], acc0);
    acc1 = fmaf(qq, wk[(size_t)d * 512 + tid + 256], acc1);
  }
  ws[WS_U + m * 4096 + h * 512 + tid] = 0.125f * acc0;
  ws[WS_U + m * 4096 + h * 512 + tid + 256] = 0.125f * acc1;
  if (m == 0 && h == 0) {
    float v = entb[tid] + entb[tid + 256];
    float s = blk_sum4(v, red, lane, wave);
    if (tid == 0) ws[WS_ENTBM] = s * (1.f / 512.f);
  }
}

// ---------------- attn_pool: SINGLE-PASS online-softmax fused score+pool ----------------
// Each wave streams rows l = wave, wave+4, ... once from HBM (depth-2 prefetch).
// Per row: 8 head scores via pair-merge butterfly (every lane ends with one full
// head sum), LDS-broadcast the 8 scores, then online-softmax accumulate the row
// into acc[8 heads][lane's 8 cols]. Deferred rescale (threshold 8): for this
// problem scores ~N(0,1e-2) so the rescale path never executes (reference m=0),
// but the guard keeps arbitrary data correct. Cross-wave combine via 32KB LDS
// in two 4-head rounds. Eliminates the old phase-C L3 re-read entirely.
__global__ __launch_bounds__(256, 2) void attn_pool_kernel(
    const float* __restrict__ trgb, const float* __restrict__ tnir, const float* __restrict__ ttir,
    const float* __restrict__ ws, float* __restrict__ Pout)
{
  const int b = blockIdx.x, m = blockIdx.y;
  const int tid = threadIdx.x, lane = tid & 63, wave = tid >> 6;
  const float* tok = ((m == 0) ? trgb : (m == 1) ? tnir : ttir) + (size_t)b * 129 * 512;
  const float* u = ws + WS_U + m * 4096;

  __shared__ float lacc[4][4][512];   // 32 KB combine stage (4 heads / round)
  __shared__ float lstat[4][16];      // per-wave m[8], s[8]
  __shared__ float tsh[4][8];         // per-row head-score broadcast

  float4 u0[8], u1[8];
#pragma unroll
  for (int h = 0; h < 8; h++) {
    u0[h] = *(const float4*)(u + h * 512 + 4 * lane);
    u1[h] = *(const float4*)(u + h * 512 + 256 + 4 * lane);
  }
  const int s0 = lane & 1, s1 = (lane >> 1) & 1, s2 = (lane >> 2) & 1;
  const int hidx = ((lane & 1) << 2) | (lane & 2) | ((lane >> 2) & 1);

  float acc[8][8];                    // [head][col: 4*lane.. / 256+4*lane..]
  float mh[8], sh[8];
#pragma unroll
  for (int h = 0; h < 8; h++) {
    mh[h] = 0.f; sh[h] = 0.f;
#pragma unroll
    for (int j = 0; j < 8; j++) acc[h][j] = 0.f;
  }

  auto process_row = [&](const float4 a, const float4 c) {
    float p[8];
#pragma unroll
    for (int h = 0; h < 8; h++)
      p[h] = a.x * u0[h].x + a.y * u0[h].y + a.z * u0[h].z + a.w * u0[h].w
           + c.x * u1[h].x + c.y * u1[h].y + c.z * u1[h].z + c.w * u1[h].w;
    // pair-merge head-distributing reduce: after xor4 each lane holds one head;
    // xor8/16/32 complete the 64-lane sum leaving EVERY lane with head hidx's total.
    float q0 = (s0 ? p[4] : p[0]) + __shfl_xor(s0 ? p[0] : p[4], 1);
    float q1 = (s0 ? p[5] : p[1]) + __shfl_xor(s0 ? p[1] : p[5], 1);
    float q2 = (s0 ? p[6] : p[2]) + __shfl_xor(s0 ? p[2] : p[6], 1);
    float q3 = (s0 ? p[7] : p[3]) + __shfl_xor(s0 ? p[3] : p[7], 1);
    float r0 = (s1 ? q2 : q0) + __shfl_xor(s1 ? q0 : q2, 2);
    float r1 = (s1 ? q3 : q1) + __shfl_xor(s1 ? q1 : q3, 2);
    float t  = (s2 ? r1 : r0) + __shfl_xor(s2 ? r0 : r1, 4);
    t += __shfl_xor(t, 8);
    t += __shfl_xor(t, 16);
    t += __shfl_xor(t, 32);
    if (lane < 8) tsh[wave][hidx] = t;   // wave-local write; read below same wave
#pragma unroll
    for (int h = 0; h < 8; h++) {
      float tv = tsh[wave][h];
      if (tv > mh[h] + 8.0f) {           // deferred rescale — cold path
        float scl = __expf(mh[h] - tv);
        sh[h] *= scl;
#pragma unroll
        for (int j = 0; j < 8; j++) acc[h][j] *= scl;
        mh[h] = tv;
      }
      float w = __expf(tv - mh[h]);
      sh[h] += w;
      acc[h][0] = fmaf(w, a.x, acc[h][0]);
      acc[h][1] = fmaf(w, a.y, acc[h][1]);
      acc[h][2] = fmaf(w, a.z, acc[h][2]);
      acc[h][3] = fmaf(w, a.w, acc[h][3]);
      acc[h][4] = fmaf(w, c.x, acc[h][4]);
      acc[h][5] = fmaf(w, c.y, acc[h][5]);
      acc[h][6] = fmaf(w, c.z, acc[h][6]);
      acc[h][7] = fmaf(w, c.w, acc[h][7]);
    }
  };

  // rows l = wave + 4*i; wave 0 gets 33 rows (incl. 128), waves 1-3 get 32
  const int nrows = (wave == 0) ? 33 : 32;
  const float* r0p = tok + (size_t)wave * 512;
  float4 a0 = *(const float4*)(r0p + 4 * lane);
  float4 c0 = *(const float4*)(r0p + 256 + 4 * lane);
  const float* r1p = tok + (size_t)(wave + 4) * 512;
  float4 a1 = *(const float4*)(r1p + 4 * lane);
  float4 c1 = *(const float4*)(r1p + 256 + 4 * lane);
  for (int i = 0; i + 2 < nrows; i++) {
    const float* np = tok + (size_t)(wave + 4 * (i + 2)) * 512;
    float4 na = *(const float4*)(np + 4 * lane);
    float4 nc = *(const float4*)(np + 256 + 4 * lane);
    process_row(a0, c0);
    a0 = a1; c0 = c1;
    a1 = na; c1 = nc;
  }
  process_row(a0, c0);
  process_row(a1, c1);

  // ---- cross-wave combine ----
  if (lane == 0) {
#pragma unroll
    for (int h = 0; h < 8; h++) {
      lstat[wave][h] = mh[h];
      lstat[wave][8 + h] = sh[h];
    }
  }
  __syncthreads();
  float fw[4][8];
#pragma unroll
  for (int h = 0; h < 8; h++) {
    float m0 = lstat[0][h], m1 = lstat[1][h], m2 = lstat[2][h], m3 = lstat[3][h];
    float Mx = fmaxf(fmaxf(m0, m1), fmaxf(m2, m3));
    float f0 = __expf(m0 - Mx), f1 = __expf(m1 - Mx);
    float f2 = __expf(m2 - Mx), f3 = __expf(m3 - Mx);
    float S = lstat[0][8 + h] * f0 + lstat[1][8 + h] * f1
            + lstat[2][8 + h] * f2 + lstat[3][8 + h] * f3;
    float is = 1.f / S;
    fw[0][h] = f0 * is; fw[1][h] = f1 * is; fw[2][h] = f2 * is; fw[3][h] = f3 * is;
  }
  float* po = Pout + (size_t)(m * 512 + b) * 4096 + 2 * tid;
#pragma unroll
  for (int hb = 0; hb < 8; hb += 4) {
    if (hb) __syncthreads();          // round-1 reads done before reuse
#pragma unroll
    for (int hh = 0; hh < 4; hh++) {
      const int h = hb + hh;
      *(float4*)&lacc[wave][hh][4 * lane] =
          make_float4(acc[h][0], acc[h][1], acc[h][2], acc[h][3]);
      *(float4*)&lacc[wave][hh][256 + 4 * lane] =
          make_float4(acc[h][4], acc[h][5], acc[h][6], acc[h][7]);
    }
    __syncthreads();
#pragma unroll
    for (int hh = 0; hh < 4; hh++) {
      const int h = hb + hh;
      float2 x0 = *(const float2*)&lacc[0][hh][2 * tid];
      float2 x1 = *(const float2*)&lacc[1][hh][2 * tid];
      float2 x2 = *(const float2*)&lacc[2][hh][2 * tid];
      float2 x3 = *(const float2*)&lacc[3][hh][2 * tid];
      float ox = x0.x * fw[0][h] + x1.x * fw[1][h] + x2.x * fw[2][h] + x3.x * fw[3][h];
      float oy = x0.y * fw[0][h] + x1.y * fw[1][h] + x2.y * fw[2][h] + x3.y * fw[3][h];
      *(float2*)(po + h * 512) = make_float2(ox, oy);
    }
  }
}

// ---------------- f32 GEMM: C = A @ B^T (+bias), 64x64 tile, 4x4 micro ----------------
__global__ __launch_bounds__(256) void gemm_bt_kernel(
    const float* __restrict__ A, const float* __restrict__ B,
    const float* __restrict__ bias, float* __restrict__ C,
    int K, int lda, int ldb, int ldc,
    long sA, long sB, long sC, int sBias, int addBias)
{
  A += (long)blockIdx.z * sA;
  B += (long)blockIdx.z * sB;
  C += (long)blockIdx.z * sC;
  const float* bp = bias + (long)blockIdx.z * sBias;
  __shared__ float As[32][68];
  __shared__ float Bs[32][68];
  const int tid = threadIdx.x;
  const int tx = tid & 15, ty = tid >> 4;
  const int rowL = tid >> 3;
  const int colv = (tid & 7) << 2;
  const int m0 = blockIdx.x * 64, n0 = blockIdx.y * 64;
  float acc[4][4] = {};
  for (int k0 = 0; k0 < K; k0 += 32) {
#pragma unroll
    for (int it = 0; it < 2; it++) {
      const int r = rowL + it * 32;
      float4 v = *(const float4*)(A + (size_t)(m0 + r) * lda + k0 + colv);
      As[colv + 0][r] = v.x; As[colv + 1][r] = v.y; As[colv + 2][r] = v.z; As[colv + 3][r] = v.w;
      float4 w = *(const float4*)(B + (size_t)(n0 + r) * ldb + k0 + colv);
      Bs[colv + 0][r] = w.x; Bs[colv + 1][r] = w.y; Bs[colv + 2][r] = w.z; Bs[colv + 3][r] = w.w;
    }
    __syncthreads();
#pragma unroll
    for (int k = 0; k < 32; k++) {
      float4 a4 = *(const float4*)&As[k][ty * 4];
      float4 b4 = *(const float4*)&Bs[k][tx * 4];
      acc[0][0] += a4.x * b4.x; acc[0][1] += a4.x * b4.y; acc[0][2] += a4.x * b4.z; acc[0][3] += a4.x * b4.w;
      acc[1][0] += a4.y * b4.x; acc[1][1] += a4.y * b4.y; acc[1][2] += a4.y * b4.z; acc[1][3] += a4.y * b4.w;
      acc[2][0] += a4.z * b4.x; acc[2][1] += a4.z * b4.y; acc[2][2] += a4.z * b4.z; acc[2][3] += a4.z * b4.w;
      acc[3][0] += a4.w * b4.x; acc[3][1] += a4.w * b4.y; acc[3][2] += a4.w * b4.z; acc[3][3] += a4.w * b4.w;
    }
    __syncthreads();
  }
  float4 bv = make_float4(0.f, 0.f, 0.f, 0.f);
  if (addBias) bv = *(const float4*)(bp + n0 + tx * 4);
#pragma unroll
  for (int i = 0; i < 4; i++) {
    float4 o;
    o.x = acc[i][0] + bv.x; o.y = acc[i][1] + bv.y;
    o.z = acc[i][2] + bv.z; o.w = acc[i][3] + bv.w;
    *(float4*)(C + (size_t)(m0 + ty * 4 + i) * ldc + n0 + tx * 4) = o;
  }
}

// ---------------- LN(attn out) + entropy + z ----------------
__global__ __launch_bounds__(256) void ln_ent_kernel(
    const float* __restrict__ out2,
    const float* __restrict__ lng, const float* __restrict__ lnb,
    const float* __restrict__ ws, float* __restrict__ hcat,
    float* __restrict__ Hout, float* __restrict__ zout)
{
  const int r = blockIdx.x;
  const int mod = r >> 9, b = r & 511;
  const int tid = threadIdx.x, lane = tid & 63, wave = tid >> 6;
  __shared__ float red[4];
  const float* x = out2 + (size_t)r * 512;
  float2 v = *(const float2*)(x + 2 * tid);
  float s = blk_sum4(v.x + v.y, red, lane, wave);
  float sq = blk_sum4(v.x * v.x + v.y * v.y, red, lane, wave);
  float mean = s * (1.f / 512.f);
  float var = sq * (1.f / 512.f) - mean * mean;
  float rstd = rsqrtf(var + 1e-5f);
  float2 g = *(const float2*)(lng + 2 * tid);
  float2 bb = *(const float2*)(lnb + 2 * tid);
  float h0 = (v.x - mean) * rstd * g.x + bb.x;
  float h1 = (v.y - mean) * rstd * g.y + bb.y;
  *(float2*)(hcat + (size_t)b * 1536 + mod * 512 + 2 * tid) = make_float2(h0, h1);
  float2 ep = make_float2(0.f, 0.f);
#pragma unroll
  for (int j = 0; j < 8; j++) {
    float2 t = *(const float2*)(ws + WS_ENTP + j * 512 + 2 * tid);
    ep.x += t.x; ep.y += t.y;
  }
  ep.x *= (1.f / 512.f); ep.y *= (1.f / 512.f);
  float fa0 = fabsf(h0) + 1e-8f, fa1 = fabsf(h1) + 1e-8f;
  float S = blk_sum4(fa0 + fa1, red, lane, wave);
  float zz = blk_sum4(h0 * ep.x + h1 * ep.y, red, lane, wave);
  float invS = 1.f / S;
  float p0 = fa0 * invS, p1 = fa1 * invS;
  float t = blk_sum4(p0 * logf(p0 + 1e-8f) + p1 * logf(p1 + 1e-8f), red, lane, wave);
  if (tid == 0) {
    Hout[mod * 512 + b] = -t;
    zout[mod * 512 + b] = zz + ws[WS_ENTBM];
  }
}

// ---------------- gate LN/relu/sigmoid + entropy softmax + fuse ----------------
__global__ __launch_bounds__(256) void gate_fuse_kernel(
    const float* __restrict__ gpre, const float* __restrict__ glng, const float* __restrict__ glnb,
    const float* __restrict__ gw2, const float* __restrict__ gb2, const float* __restrict__ gb1,
    const float* __restrict__ araw, const float* __restrict__ hcat,
    const float* __restrict__ H, const float* __restrict__ z,
    float* __restrict__ hfused)
{
  const int b = blockIdx.x;
  const int tid = threadIdx.x, lane = tid & 63, wave = tid >> 6;
  __shared__ float red[4];
  float2 v;
  {
    float2 p0 = *(const float2*)(gpre + (size_t)b * 512 + 2 * tid);
    float2 p1 = *(const float2*)(gpre + 262144 + (size_t)b * 512 + 2 * tid);
    float2 p2 = *(const float2*)(gpre + 524288 + (size_t)b * 512 + 2 * tid);
    float2 bi = *(const float2*)(gb1 + 2 * tid);
    v.x = p0.x + p1.x + p2.x + bi.x;
    v.y = p0.y + p1.y + p2.y + bi.y;
  }
  float s = blk_sum4(v.x + v.y, red, lane, wave);
  float sq = blk_sum4(v.x * v.x + v.y * v.y, red, lane, wave);
  float mean = s * (1.f / 512.f), var = sq * (1.f / 512.f) - mean * mean;
  float rstd = rsqrtf(var + 1e-5f);
  float2 g = *(const float2*)(glng + 2 * tid);
  float2 bb = *(const float2*)(glnb + 2 * tid);
  float g0 = fmaxf((v.x - mean) * rstd * g.x + bb.x, 0.f);
  float g1 = fmaxf((v.y - mean) * rstd * g.y + bb.y, 0.f);
  float d0 = blk_sum4(g0 * gw2[2 * tid] + g1 * gw2[2 * tid + 1], red, lane, wave);
  float d1 = blk_sum4(g0 * gw2[512 + 2 * tid] + g1 * gw2[512 + 2 * tid + 1], red, lane, wave);
  float d2 = blk_sum4(g0 * gw2[1024 + 2 * tid] + g1 * gw2[1024 + 2 * tid + 1], red, lane, wave);
  float ga0 = 1.f / (1.f + __expf(-(d0 + gb2[0])));
  float ga1 = 1.f / (1.f + __expf(-(d1 + gb2[1])));
  float ga2 = 1.f / (1.f + __expf(-(d2 + gb2[2])));
  float sc0 = z[b] * __expf(-H[b]);
  float sc1 = z[512 + b] * __expf(-H[512 + b]);
  float sc2 = z[1024 + b] * __expf(-H[1024 + b]);
  float mxs = fmaxf(sc0, fmaxf(sc1, sc2));
  float e0 = __expf(sc0 - mxs), e1 = __expf(sc1 - mxs), e2 = __expf(sc2 - mxs);
  float inv = 1.f / (e0 + e1 + e2);
  e0 *= inv; e1 *= inv; e2 *= inv;
  float alpha = 1.f / (1.f + __expf(-araw[0]));
  const float* hb = hcat + (size_t)b * 1536 + 2 * tid;
  float2 hr = *(const float2*)hb;
  float2 hn = *(const float2*)(hb + 512);
  float2 ht = *(const float2*)(hb + 1024);
  float2 o;
  o.x = alpha * (e0 * hr.x + e1 * hn.x + e2 * ht.x)
      + (1.f - alpha) * (ga0 * hr.x + ga1 * hn.x + ga2 * ht.x);
  o.y = alpha * (e0 * hr.y + e1 * hn.y + e2 * ht.y)
      + (1.f - alpha) * (ga0 * hr.y + ga1 * hn.y + ga2 * ht.y);
  *(float2*)(hfused + (size_t)b * 512 + 2 * tid) = o;
}

// ---------------- final LN(enh) + concat-add ----------------
__global__ __launch_bounds__(256) void final_out_kernel(
    const float* __restrict__ epre, const float* __restrict__ enb,
    const float* __restrict__ elng, const float* __restrict__ elnb,
    const float* __restrict__ hcat, float* __restrict__ out)
{
  const int b = blockIdx.x;
  const int tid = threadIdx.x, lane = tid & 63, wave = tid >> 6;
  __shared__ float red[4];
  float2 v;
  {
    float2 p0 = *(const float2*)(epre + (size_t)b * 512 + 2 * tid);
    float2 p1 = *(const float2*)(epre + 262144 + (size_t)b * 512 + 2 * tid);
    float2 bi = *(const float2*)(enb + 2 * tid);
    v.x = p0.x + p1.x + bi.x;
    v.y = p0.y + p1.y + bi.y;
  }
  float s = blk_sum4(v.x + v.y, red, lane, wave);
  float sq = blk_sum4(v.x * v.x + v.y * v.y, red, lane, wave);
  float mean = s * (1.f / 512.f), var = sq * (1.f / 512.f) - mean * mean;
  float rstd = rsqrtf(var + 1e-5f);
  float2 g = *(const float2*)(elng + 2 * tid);
  float2 bb = *(const float2*)(elnb + 2 * tid);
  float e0 = (v.x - mean) * rstd * g.x + bb.x;
  float e1 = (v.y - mean) * rstd * g.y + bb.y;
  const float* hb = hcat + (size_t)b * 1536 + 2 * tid;
  float* ob = out + (size_t)b * 1536 + 2 * tid;
#pragma unroll
  for (int mm = 0; mm < 3; mm++) {
    float2 hv = *(const float2*)(hb + mm * 512);
    *(float2*)(ob + mm * 512) = make_float2(hv.x + e0, hv.y + e1);
  }
}

extern "C" void kernel_launch(void* const* d_in, const int* in_sizes, int n_in,
                              void* d_out, int out_size, void* d_ws, size_t ws_size,
                              hipStream_t stream)
{
  const float* trgb = (const float*)d_in[0];
  const float* tnir = (const float*)d_in[1];
  const float* ttir = (const float*)d_in[2];
  const float* qrgb = (const float*)d_in[3];
  const float* qnir = (const float*)d_in[4];
  const float* qtir = (const float*)d_in[5];
  const float* inw  = (const float*)d_in[6];
  const float* inb  = (const float*)d_in[7];
  const float* outw = (const float*)d_in[8];
  const float* outb = (const float*)d_in[9];
  const float* alng = (const float*)d_in[10];
  const float* alnb = (const float*)d_in[11];
  const float* entw = (const float*)d_in[12];
  const float* entb = (const float*)d_in[13];
  const float* gw1  = (const float*)d_in[14];
  const float* gb1  = (const float*)d_in[15];
  const float* glng = (const float*)d_in[16];
  const float* glnb = (const float*)d_in[17];
  const float* gw2  = (const float*)d_in[18];
  const float* gb2  = (const float*)d_in[19];
  const float* araw = (const float*)d_in[20];
  const float* enw  = (const float*)d_in[21];
  const float* enb  = (const float*)d_in[22];
  const float* elng = (const float*)d_in[23];
  const float* elnb = (const float*)d_in[24];
  float* ws = (float*)d_ws;
  float* out = (float*)d_out;

  hipLaunchKernelGGL(prep_kernel, dim3(4, 8), dim3(256), 0, stream,
                     qrgb, qnir, qtir, inw, inb, entw, entb, ws);
  hipLaunchKernelGGL(attn_pool_kernel, dim3(512, 3), dim3(256), 0, stream,
                     trgb, tnir, ttir, ws, ws + WS_P);
  // vout = P @ Wv^T + bv (batched over 8 heads)
  hipLaunchKernelGGL(gemm_bt_kernel, dim3(24, 1, 8), dim3(256), 0, stream,
                     ws + WS_P, inw + (size_t)1024 * 512, inb + 1024, ws + WS_VOUT,
                     512, 4096, 512, 512,
                     (long)512, (long)64 * 512, (long)64, 64, 1);
  // out2 = vout @ Wo^T + bo
  hipLaunchKernelGGL(gemm_bt_kernel, dim3(24, 8, 1), dim3(256), 0, stream,
                     ws + WS_VOUT, outw, outb, ws + WS_OUT2,
                     512, 512, 512, 512, 0L, 0L, 0L, 0, 1);
  hipLaunchKernelGGL(ln_ent_kernel, dim3(1536), dim3(256), 0, stream,
                     ws + WS_OUT2, alng, alnb, ws, ws + WS_HCAT, ws + WS_H, ws + WS_Z);
  // g_pre partials = hcat @ gate_w1^T (split-K x3, bias added in gate_fuse)
  hipLaunchKernelGGL(gemm_bt_kernel, dim3(8, 8, 3), dim3(256), 0, stream,
                     ws + WS_HCAT, gw1, gb1, ws + WS_GPRE,
                     512, 1536, 1536, 512,
                     (long)512, (long)512, (long)262144, 0, 0);
  hipLaunchKernelGGL(gate_fuse_kernel, dim3(512), dim3(256), 0, stream,
                     ws + WS_GPRE, glng, glnb, gw2, gb2, gb1, araw,
                     ws + WS_HCAT, ws + WS_H, ws + WS_Z, ws + WS_HFUSED);
  // enh partials = h_fused @ enh_w^T (split-K x2, bias added in final_out)
  hipLaunchKernelGGL(gemm_bt_kernel, dim3(8, 8, 2), dim3(256), 0, stream,
                     ws + WS_HFUSED, enw, enb, ws + WS_ENHPRE,
                     256, 512, 512, 512,
                     (long)256, (long)256, (long)262144, 0, 0);
  hipLaunchKernelGGL(final_out_kernel, dim3(512), dim3(256), 0, stream,
                     ws + WS_ENHPRE, enb, elng, elnb, ws + WS_HCAT, out);
}